// Round 2
// baseline (9152.665 us; speedup 1.0000x reference)
//
#include <hip/hip_runtime.h>

#define DD 64

// ---- float max via order-preserving uint key ----
__device__ __forceinline__ unsigned fkey(float v) {
    unsigned b = __float_as_uint(v);
    return (b & 0x80000000u) ? ~b : (b | 0x80000000u);
}
__device__ __forceinline__ float funkey(unsigned k) {
    return __uint_as_float((k & 0x80000000u) ? (k & 0x7FFFFFFFu) : ~k);
}

// ---- degree count (original edges only) ----
__global__ void count_kernel(const int* __restrict__ dst, float* __restrict__ cnt, int E) {
    int e = blockIdx.x * blockDim.x + threadIdx.x;
    if (e < E) atomicAdd(&cnt[dst[e]], 1.0f);
}

// ---- SAGE neighbor-sum scatter: 64 threads per edge ----
__global__ void scatter_add(const int* __restrict__ src, const int* __restrict__ dst,
                            const float* __restrict__ x, float* __restrict__ agg, int E) {
    long long tid = (long long)blockIdx.x * blockDim.x + threadIdx.x;
    int e = (int)(tid >> 6), f = (int)(tid & 63);
    if (e < E) {
        int s = src[e], d = dst[e];
        atomicAdd(&agg[d * DD + f], x[s * DD + f]);
    }
}

// ---- SAGE transform: out = (agg/max(cnt,1)) @ Wl^T + cur @ Wr^T + b ----
__global__ __launch_bounds__(256) void sage_transform(
    const float* __restrict__ cur, const float* __restrict__ agg,
    const float* __restrict__ cnt, const float* __restrict__ Wl,
    const float* __restrict__ Wr, const float* __restrict__ b,
    float* __restrict__ out, int n, int do_relu) {
    __shared__ float sWlT[64 * 64], sWrT[64 * 64];
    __shared__ float sx[4][64], sm[4][64];
    int t = threadIdx.x;
#pragma unroll
    for (int i = 0; i < 16; i++) {
        int g = t + i * 256;
        int f = g >> 6, k = g & 63;
        sWlT[k * 64 + f] = Wl[g];
        sWrT[k * 64 + f] = Wr[g];
    }
    int r = t >> 6, f = t & 63;
    int row = blockIdx.x * 4 + r;
    float c = fmaxf(cnt[row], 1.0f);
    sx[r][f] = cur[row * 64 + f];
    sm[r][f] = agg[row * 64 + f] / c;
    __syncthreads();
    float acc = b[f];
#pragma unroll
    for (int k = 0; k < 64; k++)
        acc += sm[r][k] * sWlT[k * 64 + f] + sx[r][k] * sWrT[k * 64 + f];
    if (do_relu) acc = fmaxf(acc, 0.0f);
    out[row * 64 + f] = acc;
}

// ---- plain 64x64 GEMM: out = in @ W^T ----
__global__ __launch_bounds__(256) void gemm64(
    const float* __restrict__ in, const float* __restrict__ W,
    float* __restrict__ out, int n) {
    __shared__ float sWT[64 * 64];
    __shared__ float sx[4][64];
    int t = threadIdx.x;
#pragma unroll
    for (int i = 0; i < 16; i++) {
        int g = t + i * 256;
        sWT[(g & 63) * 64 + (g >> 6)] = W[g];
    }
    int r = t >> 6, f = t & 63;
    int row = blockIdx.x * 4 + r;
    sx[r][f] = in[row * 64 + f];
    __syncthreads();
    float acc = 0.0f;
#pragma unroll
    for (int k = 0; k < 64; k++)
        acc += sx[r][k] * sWT[k * 64 + f];
    out[row * 64 + f] = acc;
}

// ---- per-node attention dots: asv = h.a_src, adv = h.a_dst ----
__global__ __launch_bounds__(256) void attn_sums(
    const float* __restrict__ h, const float* __restrict__ a_src,
    const float* __restrict__ a_dst, float* __restrict__ asv,
    float* __restrict__ adv, int n) {
    int t = threadIdx.x;
    int r = t >> 6, f = t & 63;
    int row = blockIdx.x * 4 + r;
    float v = h[row * 64 + f];
    float a = v * a_src[f];
    float d = v * a_dst[f];
#pragma unroll
    for (int o = 32; o >= 1; o >>= 1) {
        a += __shfl_xor(a, o);
        d += __shfl_xor(d, o);
    }
    if (f == 0) { asv[row] = a; adv[row] = d; }
}

// ---- GAT edge pass 1: segment max ----
__global__ void edge_max(const int* __restrict__ src, const int* __restrict__ dst,
                         const float* __restrict__ asv, const float* __restrict__ adv,
                         unsigned* __restrict__ mmax, int E, int n) {
    int e = blockIdx.x * blockDim.x + threadIdx.x;
    if (e >= E + n) return;
    int s, d;
    if (e < E) { s = src[e]; d = dst[e]; } else { s = d = e - E; }
    float ev = asv[s] + adv[d];
    ev = ev > 0.0f ? ev : 0.2f * ev;
    atomicMax(&mmax[d], fkey(ev));
}

// ---- GAT edge pass 2: segment sum of exp ----
__global__ void edge_sum(const int* __restrict__ src, const int* __restrict__ dst,
                         const float* __restrict__ asv, const float* __restrict__ adv,
                         const unsigned* __restrict__ mmax, float* __restrict__ denom,
                         int E, int n) {
    int e = blockIdx.x * blockDim.x + threadIdx.x;
    if (e >= E + n) return;
    int s, d;
    if (e < E) { s = src[e]; d = dst[e]; } else { s = d = e - E; }
    float ev = asv[s] + adv[d];
    ev = ev > 0.0f ? ev : 0.2f * ev;
    atomicAdd(&denom[d], expf(ev - funkey(mmax[d])));
}

// ---- GAT edge pass 3: weighted accumulate, 64 threads/edge ----
__global__ void edge_accum(const int* __restrict__ src, const int* __restrict__ dst,
                           const float* __restrict__ asv, const float* __restrict__ adv,
                           const unsigned* __restrict__ mmax, const float* __restrict__ denom,
                           const float* __restrict__ h, float* __restrict__ out, int E, int n) {
    long long tid = (long long)blockIdx.x * blockDim.x + threadIdx.x;
    int e = (int)(tid >> 6), f = (int)(tid & 63);
    if (e >= E + n) return;
    int s, d;
    if (e < E) { s = src[e]; d = dst[e]; } else { s = d = e - E; }
    float ev = asv[s] + adv[d];
    ev = ev > 0.0f ? ev : 0.2f * ev;
    float alpha = expf(ev - funkey(mmax[d])) / fmaxf(denom[d], 1e-16f);
    atomicAdd(&out[d * DD + f], alpha * h[s * DD + f]);
}

// ---- bias + optional relu ----
__global__ void bias_act(float* __restrict__ out, const float* __restrict__ b,
                         int total, int do_relu) {
    int i = blockIdx.x * blockDim.x + threadIdx.x;
    if (i < total) {
        float v = out[i] + b[i & 63];
        out[i] = do_relu ? fmaxf(v, 0.0f) : v;
    }
}

// ---- fused projection MLP: 64 -> 64 -> 32 -> 16 ----
__global__ __launch_bounds__(256) void mlp_kernel(
    const float* __restrict__ in,
    const float* __restrict__ w1, const float* __restrict__ b1,
    const float* __restrict__ w2, const float* __restrict__ b2,
    const float* __restrict__ w3, const float* __restrict__ b3,
    float* __restrict__ out, int n) {
    __shared__ float sw1T[64 * 64], sw2T[64 * 32], sw3T[32 * 16];
    __shared__ float sx[4][64], st1[4][64], st2[4][32];
    int t = threadIdx.x;
#pragma unroll
    for (int i = 0; i < 16; i++) { int g = t + i * 256; sw1T[(g & 63) * 64 + (g >> 6)] = w1[g]; }
#pragma unroll
    for (int i = 0; i < 8; i++) { int g = t + i * 256; sw2T[(g & 63) * 32 + (g >> 6)] = w2[g]; }
#pragma unroll
    for (int i = 0; i < 2; i++) { int g = t + i * 256; sw3T[(g & 31) * 16 + (g >> 5)] = w3[g]; }
    int r = t >> 6, f = t & 63;
    int row = blockIdx.x * 4 + r;
    sx[r][f] = in[row * 64 + f];
    __syncthreads();
    float a1 = b1[f];
#pragma unroll
    for (int k = 0; k < 64; k++) a1 += sx[r][k] * sw1T[k * 64 + f];
    st1[r][f] = fmaxf(a1, 0.0f);
    __syncthreads();
    if (f < 32) {
        float a2 = b2[f];
#pragma unroll
        for (int k = 0; k < 64; k++) a2 += st1[r][k] * sw2T[k * 32 + f];
        st2[r][f] = fmaxf(a2, 0.0f);
    }
    __syncthreads();
    if (f < 16) {
        float a3 = b3[f];
#pragma unroll
        for (int k = 0; k < 32; k++) a3 += st2[r][k] * sw3T[k * 16 + f];
        out[row * 16 + f] = a3;
    }
}

extern "C" void kernel_launch(void* const* d_in, const int* in_sizes, int n_in,
                              void* d_out, int out_size, void* d_ws, size_t ws_size,
                              hipStream_t stream) {
    const float* x        = (const float*)d_in[0];
    const int*   ei       = (const int*)d_in[1];   // harness passes integers as int32
    const float* sage_Wl  = (const float*)d_in[2];
    const float* sage_Wr  = (const float*)d_in[3];
    const float* sage_b   = (const float*)d_in[4];
    const float* gat_W    = (const float*)d_in[5];
    const float* gat_as   = (const float*)d_in[6];
    const float* gat_ad   = (const float*)d_in[7];
    const float* gat_b    = (const float*)d_in[8];
    const float* p1W = (const float*)d_in[9],  *p1b = (const float*)d_in[10];
    const float* p2W = (const float*)d_in[11], *p2b = (const float*)d_in[12];
    const float* p3W = (const float*)d_in[13], *p3b = (const float*)d_in[14];

    int n = in_sizes[0] / 64;
    int E = in_sizes[1] / 2;
    const int* src = ei;
    const int* dst = ei + E;

    char* w = (char*)d_ws;
    float* bufA   = (float*)w;  w += (size_t)n * 64 * 4;
    float* bufB   = (float*)w;  w += (size_t)n * 64 * 4;
    float* cnt    = (float*)w;  w += (size_t)n * 4;
    float* asv    = (float*)w;  w += (size_t)n * 4;
    float* adv    = (float*)w;  w += (size_t)n * 4;
    unsigned* mmax = (unsigned*)w; w += (size_t)n * 4;
    float* denom  = (float*)w;  w += (size_t)n * 4;

    // degree once (edge structure fixed across layers)
    hipMemsetAsync(cnt, 0, (size_t)n * 4, stream);
    count_kernel<<<(E + 255) / 256, 256, 0, stream>>>(dst, cnt, E);

    const float* cur = x;

    // ---- 4 SAGE layers ----
    for (int l = 0; l < 4; l++) {
        float* other = (cur == (const float*)bufA) ? bufB : bufA;
        hipMemsetAsync(other, 0, (size_t)n * 64 * 4, stream);
        long long tot = (long long)E * 64;
        scatter_add<<<(int)((tot + 255) / 256), 256, 0, stream>>>(src, dst, cur, other, E);
        sage_transform<<<n / 4, 256, 0, stream>>>(cur, other, cnt,
            sage_Wl + l * 4096, sage_Wr + l * 4096, sage_b + l * 64,
            other, n, l < 3 ? 1 : 0);
        cur = other;
    }

    // ---- 3 GAT layers (with self-loops) ----
    int M = E + n;
    for (int l = 0; l < 3; l++) {
        float* other = (cur == (const float*)bufA) ? bufB : bufA;
        float* ob = (float*)cur;  // cur is a ws buffer by now; reuse as output
        gemm64<<<n / 4, 256, 0, stream>>>(cur, gat_W + l * 4096, other, n);
        attn_sums<<<n / 4, 256, 0, stream>>>(other, gat_as + l * 64, gat_ad + l * 64, asv, adv, n);
        hipMemsetAsync(mmax, 0, (size_t)n * 4, stream);
        hipMemsetAsync(denom, 0, (size_t)n * 4, stream);
        edge_max<<<(M + 255) / 256, 256, 0, stream>>>(src, dst, asv, adv, mmax, E, n);
        edge_sum<<<(M + 255) / 256, 256, 0, stream>>>(src, dst, asv, adv, mmax, denom, E, n);
        hipMemsetAsync(ob, 0, (size_t)n * 64 * 4, stream);
        long long tot = (long long)M * 64;
        edge_accum<<<(int)((tot + 255) / 256), 256, 0, stream>>>(src, dst, asv, adv, mmax, denom, other, ob, E, n);
        bias_act<<<(n * 64 + 255) / 256, 256, 0, stream>>>(ob, gat_b + l * 64, n * 64, l < 2 ? 1 : 0);
        cur = ob;
    }

    // ---- projection MLP ----
    mlp_kernel<<<n / 4, 256, 0, stream>>>(cur, p1W, p1b, p2W, p2b, p3W, p3b,
                                          (float*)d_out, n);
}

// Round 3
// 1822.124 us; speedup vs baseline: 5.0231x; 5.0231x over previous
//
#include <hip/hip_runtime.h>

__device__ __forceinline__ float lrelu(float v){ return v > 0.f ? v : 0.2f*v; }

// ================= CSR build =================
__global__ void deg_count(const int* __restrict__ dst, int* __restrict__ deg, int E){
  int e = blockIdx.x*blockDim.x + threadIdx.x;
  if (e < E) atomicAdd(&deg[dst[e]], 1);
}

__global__ void scan_block(const int* __restrict__ deg, int* __restrict__ rowptr,
                           int* __restrict__ bsum){
  __shared__ int s[256];
  int t = threadIdx.x; int i = blockIdx.x*256 + t;
  int v = deg[i];
  s[t] = v; __syncthreads();
  for (int off=1; off<256; off<<=1){
    int a = (t>=off)? s[t-off] : 0; __syncthreads();
    s[t] += a; __syncthreads();
  }
  rowptr[i+1] = s[t];
  if (t==255) bsum[blockIdx.x] = s[255];
}

// 1 block, 256 threads, exactly 1024 entries -> in-place exclusive prefix
__global__ void scan_top(int* __restrict__ bsum){
  __shared__ int s[256];
  int t = threadIdx.x;
  int v0=bsum[t*4], v1=bsum[t*4+1], v2=bsum[t*4+2], v3=bsum[t*4+3];
  s[t] = v0+v1+v2+v3; __syncthreads();
  for (int off=1; off<256; off<<=1){
    int a = (t>=off)? s[t-off] : 0; __syncthreads();
    s[t] += a; __syncthreads();
  }
  int excl = (t==0)? 0 : s[t-1];
  bsum[t*4]   = excl;
  bsum[t*4+1] = excl+v0;
  bsum[t*4+2] = excl+v0+v1;
  bsum[t*4+3] = excl+v0+v1+v2;
}

__global__ void scan_add(int* __restrict__ rowptr, const int* __restrict__ bsum){
  int i = blockIdx.x*256 + threadIdx.x;
  rowptr[i+1] += bsum[blockIdx.x];
  if (i == 0) rowptr[0] = 0;
}

__global__ void copy_wp(const int* __restrict__ rowptr, int* __restrict__ wp){
  int i = blockIdx.x*256 + threadIdx.x;
  wp[i] = rowptr[i];
}

__global__ void fill_csr(const int* __restrict__ src, const int* __restrict__ dst,
                         int* __restrict__ wp, int* __restrict__ col, int E){
  int e = blockIdx.x*blockDim.x + threadIdx.x;
  if (e < E){
    int d = dst[e];
    int pos = atomicAdd(&wp[d], 1);
    col[pos] = src[e];
  }
}

// ================= SAGE: fused gather-mean + dual GEMM =================
// out = mean(nbr x) @ Wl^T + x @ Wr^T + b  [+relu]; 64 rows/block, 4 waves x 16 rows
__global__ __launch_bounds__(256) void sage_fused(
    const float* __restrict__ cur, const int* __restrict__ rowptr,
    const int* __restrict__ col, const float* __restrict__ Wl,
    const float* __restrict__ Wr, const float* __restrict__ bias,
    float* __restrict__ out, int do_relu){
  __shared__ float sM[64*64];
  __shared__ float sX[64*64];
  int t = threadIdx.x;
  int f = t & 63;
  int row0 = blockIdx.x * 64;
  // stage X tile (coalesced float4)
  {
    float4* d = (float4*)sX;
    const float4* g = (const float4*)(cur + (size_t)row0*64);
#pragma unroll
    for (int i=0;i<4;i++) d[t + i*256] = g[t + i*256];
  }
  int rbase = __builtin_amdgcn_readfirstlane((t>>6)*16);
  // gather neighbor means for this wave's 16 rows (wave-per-row, lane=feature)
  for (int rr=0; rr<16; rr++){
    int row = row0 + rbase + rr;
    int beg = rowptr[row], end = rowptr[row+1];
    float acc = 0.f;
    for (int j=beg; j<end; j++){
      int s = col[j];
      acc += cur[(size_t)s*64 + f];
    }
    sM[(rbase+rr)*64 + f] = acc / fmaxf((float)(end-beg), 1.0f);
  }
  // weights into registers: lane f holds row f of Wl and Wr
  float4 wl[16], wr[16];
  const float4* Wl4 = (const float4*)(Wl + f*64);
  const float4* Wr4 = (const float4*)(Wr + f*64);
#pragma unroll
  for (int kk=0; kk<16; kk++){ wl[kk]=Wl4[kk]; wr[kk]=Wr4[kk]; }
  float bf = bias[f];
  __syncthreads();
#pragma unroll
  for (int rr=0; rr<16; rr++){
    const float4* m4 = (const float4*)(sM + (rbase+rr)*64);  // broadcast reads
    const float4* x4 = (const float4*)(sX + (rbase+rr)*64);
    float acc = bf;
#pragma unroll
    for (int kk=0; kk<16; kk++){
      float4 a=m4[kk], c=x4[kk], u=wl[kk], v=wr[kk];
      acc += a.x*u.x + a.y*u.y + a.z*u.z + a.w*u.w;
      acc += c.x*v.x + c.y*v.y + c.z*v.z + c.w*v.w;
    }
    if (do_relu) acc = fmaxf(acc, 0.f);
    out[(size_t)(row0+rbase+rr)*64 + f] = acc;
  }
}

// ================= GAT linear: h = x @ W^T =================
__global__ __launch_bounds__(256) void gat_gemm(
    const float* __restrict__ cur, const float* __restrict__ W,
    float* __restrict__ out){
  __shared__ float sX[64*64];
  int t = threadIdx.x, f = t & 63;
  int row0 = blockIdx.x * 64;
  {
    float4* d = (float4*)sX;
    const float4* g = (const float4*)(cur + (size_t)row0*64);
#pragma unroll
    for (int i=0;i<4;i++) d[t + i*256] = g[t + i*256];
  }
  float4 wv[16];
  const float4* W4 = (const float4*)(W + f*64);
#pragma unroll
  for (int kk=0; kk<16; kk++) wv[kk] = W4[kk];
  int rbase = __builtin_amdgcn_readfirstlane((t>>6)*16);
  __syncthreads();
#pragma unroll
  for (int rr=0; rr<16; rr++){
    const float4* x4 = (const float4*)(sX + (rbase+rr)*64);
    float acc = 0.f;
#pragma unroll
    for (int kk=0; kk<16; kk++){
      float4 c=x4[kk], v=wv[kk];
      acc += c.x*v.x + c.y*v.y + c.z*v.z + c.w*v.w;
    }
    out[(size_t)(row0+rbase+rr)*64 + f] = acc;
  }
}

// ================= attention per-node dots =================
__global__ __launch_bounds__(256) void attn_sums(
    const float* __restrict__ h, const float* __restrict__ a_src,
    const float* __restrict__ a_dst, float* __restrict__ asv,
    float* __restrict__ adv, int n){
  int t = threadIdx.x;
  int r = t >> 6, f = t & 63;
  int row = blockIdx.x*4 + r;
  float v = h[(size_t)row*64 + f];
  float a = v * a_src[f];
  float d = v * a_dst[f];
#pragma unroll
  for (int o = 32; o >= 1; o >>= 1){
    a += __shfl_xor(a, o);
    d += __shfl_xor(d, o);
  }
  if (f == 0){ asv[row] = a; adv[row] = d; }
}

// ================= GAT fused softmax + aggregate + bias (+relu) =================
// one wave per dst node; self-loop included; online softmax (wave-uniform m, den)
__global__ __launch_bounds__(256) void gat_agg(
    const float* __restrict__ h, const int* __restrict__ rowptr,
    const int* __restrict__ col, const float* __restrict__ asv,
    const float* __restrict__ adv, const float* __restrict__ bias,
    float* __restrict__ out, int do_relu){
  int t = threadIdx.x;
  int f = t & 63;
  int v = __builtin_amdgcn_readfirstlane((blockIdx.x*256 + t) >> 6);
  int beg = rowptr[v], end = rowptr[v+1];
  float advv = adv[v];
  float eself = lrelu(asv[v] + advv);
  float m = eself, den = 1.0f;     // den tracks exp(eself - m) + edge terms
  for (int j0 = beg; j0 < end; j0 += 64){
    int j = j0 + f;
    float e = (j < end) ? lrelu(asv[col[j]] + advv) : -1e30f;
    float cm = e;
#pragma unroll
    for (int off = 32; off >= 1; off >>= 1) cm = fmaxf(cm, __shfl_xor(cm, off));
    if (cm > m){ den *= expf(m - cm); m = cm; }
    float p = (j < end) ? expf(e - m) : 0.f;
#pragma unroll
    for (int off = 32; off >= 1; off >>= 1) p += __shfl_xor(p, off);
    den += p;
  }
  float acc = expf(eself - m) * h[(size_t)v*64 + f];   // self contribution
  for (int j = beg; j < end; j++){
    int s = col[j];                                     // wave-uniform
    float e = lrelu(asv[s] + advv);
    acc += expf(e - m) * h[(size_t)s*64 + f];
  }
  acc = acc / fmaxf(den, 1e-16f) + bias[f];
  if (do_relu) acc = fmaxf(acc, 0.f);
  out[(size_t)v*64 + f] = acc;
}

// ================= fused MLP 64->64->32->16 (64 rows/block) =================
__global__ __launch_bounds__(256) void mlp3(
    const float* __restrict__ in,
    const float* __restrict__ w1, const float* __restrict__ b1,
    const float* __restrict__ w2, const float* __restrict__ b2,
    const float* __restrict__ w3, const float* __restrict__ b3,
    float* __restrict__ out){
  __shared__ float sX[64*64];
  __shared__ float sH1[64*64];
  __shared__ float sH2[64*32];
  int t = threadIdx.x, f = t & 63;
  int row0 = blockIdx.x * 64;
  {
    float4* d = (float4*)sX;
    const float4* g = (const float4*)(in + (size_t)row0*64);
#pragma unroll
    for (int i=0;i<4;i++) d[t + i*256] = g[t + i*256];
  }
  int rbase = __builtin_amdgcn_readfirstlane((t>>6)*16);
  // layer 1: 64->64
  float4 wv[16];
  { const float4* W4 = (const float4*)(w1 + f*64);
#pragma unroll
    for (int kk=0; kk<16; kk++) wv[kk] = W4[kk]; }
  float bf = b1[f];
  __syncthreads();
#pragma unroll
  for (int rr=0; rr<16; rr++){
    const float4* x4 = (const float4*)(sX + (rbase+rr)*64);
    float acc = bf;
#pragma unroll
    for (int kk=0; kk<16; kk++){ float4 c=x4[kk], w=wv[kk];
      acc += c.x*w.x + c.y*w.y + c.z*w.z + c.w*w.w; }
    sH1[(rbase+rr)*64 + f] = fmaxf(acc, 0.f);
  }
  __syncthreads();
  // layer 2: 64->32 ; lanes split: f2 = f&31, two rows per step
  int f2 = f & 31, hi = f >> 5;
  { const float4* W4 = (const float4*)(w2 + f2*64);
#pragma unroll
    for (int kk=0; kk<16; kk++) wv[kk] = W4[kk]; }
  float bf2 = b2[f2];
#pragma unroll
  for (int rr=0; rr<8; rr++){
    int rloc = rbase + rr*2 + hi;
    const float4* x4 = (const float4*)(sH1 + rloc*64);
    float acc = bf2;
#pragma unroll
    for (int kk=0; kk<16; kk++){ float4 c=x4[kk], w=wv[kk];
      acc += c.x*w.x + c.y*w.y + c.z*w.z + c.w*w.w; }
    sH2[rloc*32 + f2] = fmaxf(acc, 0.f);
  }
  __syncthreads();
  // layer 3: 32->16 ; f3 = f&15, four rows per step
  int f3 = f & 15, hi2 = f >> 4;
  float4 w3v[8];
  { const float4* W4 = (const float4*)(w3 + f3*32);
#pragma unroll
    for (int kk=0; kk<8; kk++) w3v[kk] = W4[kk]; }
  float bf3 = b3[f3];
#pragma unroll
  for (int rr=0; rr<4; rr++){
    int rloc = rbase + rr*4 + hi2;
    const float4* x4 = (const float4*)(sH2 + rloc*32);
    float acc = bf3;
#pragma unroll
    for (int kk=0; kk<8; kk++){ float4 c=x4[kk], w=w3v[kk];
      acc += c.x*w.x + c.y*w.y + c.z*w.z + c.w*w.w; }
    out[(size_t)(row0+rloc)*16 + f3] = acc;
  }
}

extern "C" void kernel_launch(void* const* d_in, const int* in_sizes, int n_in,
                              void* d_out, int out_size, void* d_ws, size_t ws_size,
                              hipStream_t stream) {
    const float* x        = (const float*)d_in[0];
    const int*   ei       = (const int*)d_in[1];
    const float* sage_Wl  = (const float*)d_in[2];
    const float* sage_Wr  = (const float*)d_in[3];
    const float* sage_b   = (const float*)d_in[4];
    const float* gat_W    = (const float*)d_in[5];
    const float* gat_as   = (const float*)d_in[6];
    const float* gat_ad   = (const float*)d_in[7];
    const float* gat_b    = (const float*)d_in[8];
    const float* p1W = (const float*)d_in[9],  *p1b = (const float*)d_in[10];
    const float* p2W = (const float*)d_in[11], *p2b = (const float*)d_in[12];
    const float* p3W = (const float*)d_in[13], *p3b = (const float*)d_in[14];

    int n = in_sizes[0] / 64;        // 262144
    int E = in_sizes[1] / 2;         // 1048576
    const int* src = ei;
    const int* dst = ei + E;

    size_t N64 = (size_t)n * 64;
    float* bufA   = (float*)d_ws;
    float* bufB   = bufA + N64;
    int*   deg    = (int*)(bufB + N64);
    int*   rowptr = deg + n;
    int*   wp     = rowptr + (n + 1);
    int*   col    = wp + n;
    int*   bsum   = col + E;
    float* asv    = (float*)(bsum + 1024);
    float* adv    = asv + n;

    int nb = n / 256;                 // 1024

    // ---- CSR build (per launch; deterministic enough: fp32 reorder noise only) ----
    hipMemsetAsync(deg, 0, (size_t)n * 4, stream);
    deg_count<<<(E + 255) / 256, 256, 0, stream>>>(dst, deg, E);
    scan_block<<<nb, 256, 0, stream>>>(deg, rowptr, bsum);
    scan_top<<<1, 256, 0, stream>>>(bsum);
    scan_add<<<nb, 256, 0, stream>>>(rowptr, bsum);
    copy_wp<<<nb, 256, 0, stream>>>(rowptr, wp);
    fill_csr<<<(E + 255) / 256, 256, 0, stream>>>(src, dst, wp, col, E);

    // ---- 4 SAGE layers (fused gather-mean + dual GEMM) ----
    const float* cur = x;
    float* nxt = bufA;
    for (int l = 0; l < 4; l++){
        sage_fused<<<n / 64, 256, 0, stream>>>(cur, rowptr, col,
            sage_Wl + l*4096, sage_Wr + l*4096, sage_b + l*64, nxt, l < 3 ? 1 : 0);
        cur = nxt;
        nxt = (nxt == bufA) ? bufB : bufA;
    }
    // cur = bufB, nxt = bufA here

    // ---- 3 GAT layers ----
    for (int l = 0; l < 3; l++){
        gat_gemm<<<n / 64, 256, 0, stream>>>(cur, gat_W + l*4096, nxt);  // h -> nxt
        attn_sums<<<n / 4, 256, 0, stream>>>(nxt, gat_as + l*64, gat_ad + l*64, asv, adv, n);
        gat_agg<<<n / 4, 256, 0, stream>>>(nxt, rowptr, col, asv, adv,
                                           gat_b + l*64, (float*)cur, l < 2 ? 1 : 0);
        // output overwrote cur in place (reads only h=nxt); cur unchanged pointer
    }

    // ---- projection MLP ----
    mlp3<<<n / 64, 256, 0, stream>>>(cur, p1W, p1b, p2W, p2b, p3W, p3b, (float*)d_out);
}

// Round 4
// 1128.369 us; speedup vs baseline: 8.1114x; 1.6148x over previous
//
#include <hip/hip_runtime.h>

__device__ __forceinline__ float lrelu(float v){ return v > 0.f ? v : 0.2f*v; }
__device__ __forceinline__ void add4(float4& a, const float4 v){
  a.x += v.x; a.y += v.y; a.z += v.z; a.w += v.w; }
__device__ __forceinline__ void fma4(float4& a, float w, const float4 v){
  a.x += w*v.x; a.y += w*v.y; a.z += w*v.z; a.w += w*v.w; }
__device__ __forceinline__ void mul4(float4& a, float w){
  a.x *= w; a.y *= w; a.z *= w; a.w *= w; }

// ================= CSR build =================
__global__ void deg_count(const int* __restrict__ dst, int* __restrict__ deg, int E){
  int e = blockIdx.x*blockDim.x + threadIdx.x;
  if (e < E) atomicAdd(&deg[dst[e]], 1);
}

__global__ void scan_block(const int* __restrict__ deg, int* __restrict__ rowptr,
                           int* __restrict__ bsum){
  __shared__ int s[256];
  int t = threadIdx.x; int i = blockIdx.x*256 + t;
  int v = deg[i];
  s[t] = v; __syncthreads();
  for (int off=1; off<256; off<<=1){
    int a = (t>=off)? s[t-off] : 0; __syncthreads();
    s[t] += a; __syncthreads();
  }
  rowptr[i+1] = s[t];
  if (t==255) bsum[blockIdx.x] = s[255];
}

// 1 block, 256 threads, exactly 1024 entries -> in-place exclusive prefix
__global__ void scan_top(int* __restrict__ bsum){
  __shared__ int s[256];
  int t = threadIdx.x;
  int v0=bsum[t*4], v1=bsum[t*4+1], v2=bsum[t*4+2], v3=bsum[t*4+3];
  s[t] = v0+v1+v2+v3; __syncthreads();
  for (int off=1; off<256; off<<=1){
    int a = (t>=off)? s[t-off] : 0; __syncthreads();
    s[t] += a; __syncthreads();
  }
  int excl = (t==0)? 0 : s[t-1];
  bsum[t*4]   = excl;
  bsum[t*4+1] = excl+v0;
  bsum[t*4+2] = excl+v0+v1;
  bsum[t*4+3] = excl+v0+v1+v2;
}

__global__ void scan_add(int* __restrict__ rowptr, const int* __restrict__ bsum){
  int i = blockIdx.x*256 + threadIdx.x;
  rowptr[i+1] += bsum[blockIdx.x];
  if (i == 0) rowptr[0] = 0;
}

__global__ void copy_wp(const int* __restrict__ rowptr, int* __restrict__ wp){
  int i = blockIdx.x*256 + threadIdx.x;
  wp[i] = rowptr[i];
}

__global__ void fill_csr(const int* __restrict__ src, const int* __restrict__ dst,
                         int* __restrict__ wp, int* __restrict__ col, int E){
  int e = blockIdx.x*blockDim.x + threadIdx.x;
  if (e < E){
    int d = dst[e];
    int pos = atomicAdd(&wp[d], 1);
    col[pos] = src[e];
  }
}

// ================= SAGE: fused gather-mean + dual GEMM =================
// 64 rows/block. Gather: lane=(row,quarter) -> lane-parallel, ILP-unrolled.
__global__ __launch_bounds__(256) void sage_fused(
    const float* __restrict__ cur, const int* __restrict__ rowptr,
    const int* __restrict__ col, const float* __restrict__ Wl,
    const float* __restrict__ Wr, const float* __restrict__ bias,
    float* __restrict__ out, int do_relu){
  __shared__ float sM[64*64];
  __shared__ float sX[64*64];
  __shared__ int srp[65];
  int t = threadIdx.x;
  int row0 = blockIdx.x * 64;
  if (t < 65) srp[t] = rowptr[row0 + t];
  {
    float4* d = (float4*)sX;
    const float4* g = (const float4*)(cur + (size_t)row0*64);
#pragma unroll
    for (int i=0;i<4;i++) d[t + i*256] = g[t + i*256];
  }
  __syncthreads();
  // ---- gather-mean: 4 lanes per row, each owns 16 features ----
  {
    int l = t & 63;
    int r = ((t >> 6) << 4) + (l >> 2);   // local row 0..63
    int q = l & 3;                        // feature quarter
    int beg = srp[r], end = srp[r+1];
    const float4* base = (const float4*)cur;
    float4 a0 = {0,0,0,0}, a1 = a0, a2 = a0, a3 = a0;
    int j = beg;
    for (; j + 2 <= end; j += 2){
      int s0 = col[j], s1 = col[j+1];
      const float4* p0 = base + (size_t)s0*16 + q*4;
      const float4* p1 = base + (size_t)s1*16 + q*4;
      float4 u0=p0[0], u1=p0[1], u2=p0[2], u3=p0[3];
      float4 w0=p1[0], w1=p1[1], w2=p1[2], w3=p1[3];
      add4(a0,u0); add4(a1,u1); add4(a2,u2); add4(a3,u3);
      add4(a0,w0); add4(a1,w1); add4(a2,w2); add4(a3,w3);
    }
    if (j < end){
      int s0 = col[j];
      const float4* p0 = base + (size_t)s0*16 + q*4;
      add4(a0,p0[0]); add4(a1,p0[1]); add4(a2,p0[2]); add4(a3,p0[3]);
    }
    float rdeg = 1.f / fmaxf((float)(end-beg), 1.f);
    mul4(a0,rdeg); mul4(a1,rdeg); mul4(a2,rdeg); mul4(a3,rdeg);
    float4* sm4 = (float4*)(sM + r*64 + q*16);
    sm4[0]=a0; sm4[1]=a1; sm4[2]=a2; sm4[3]=a3;
  }
  __syncthreads();
  // ---- dual GEMM, two weight passes to limit VGPR peak ----
  int f = t & 63;
  int rbase = (t >> 6) * 16;
  float acc[16];
  {
    float4 wv[16];
    const float4* W4 = (const float4*)(Wr + f*64);
#pragma unroll
    for (int kk=0; kk<16; kk++) wv[kk] = W4[kk];
#pragma unroll
    for (int rr=0; rr<16; rr++){
      const float4* x4 = (const float4*)(sX + (rbase+rr)*64);
      float s = 0.f;
#pragma unroll
      for (int kk=0; kk<16; kk++){ float4 c=x4[kk], w=wv[kk];
        s += c.x*w.x + c.y*w.y + c.z*w.z + c.w*w.w; }
      acc[rr] = s;
    }
  }
  {
    float4 wv[16];
    const float4* W4 = (const float4*)(Wl + f*64);
#pragma unroll
    for (int kk=0; kk<16; kk++) wv[kk] = W4[kk];
    float bf = bias[f];
#pragma unroll
    for (int rr=0; rr<16; rr++){
      const float4* m4 = (const float4*)(sM + (rbase+rr)*64);
      float s = acc[rr] + bf;
#pragma unroll
      for (int kk=0; kk<16; kk++){ float4 c=m4[kk], w=wv[kk];
        s += c.x*w.x + c.y*w.y + c.z*w.z + c.w*w.w; }
      if (do_relu) s = fmaxf(s, 0.f);
      out[(size_t)(row0+rbase+rr)*64 + f] = s;
    }
  }
}

// ================= GAT linear + fused attention dots =================
__global__ __launch_bounds__(256) void gat_gemm_attn(
    const float* __restrict__ cur, const float* __restrict__ W,
    const float* __restrict__ a_src, const float* __restrict__ a_dst,
    float* __restrict__ h, float* __restrict__ asv, float* __restrict__ adv){
  __shared__ float sX[64*64];
  int t = threadIdx.x, f = t & 63;
  int row0 = blockIdx.x * 64;
  {
    float4* d = (float4*)sX;
    const float4* g = (const float4*)(cur + (size_t)row0*64);
#pragma unroll
    for (int i=0;i<4;i++) d[t + i*256] = g[t + i*256];
  }
  float4 wv[16];
  const float4* W4 = (const float4*)(W + f*64);
#pragma unroll
  for (int kk=0; kk<16; kk++) wv[kk] = W4[kk];
  float as = a_src[f], ad = a_dst[f];
  int rbase = (t >> 6) * 16;
  __syncthreads();
#pragma unroll
  for (int rr=0; rr<16; rr++){
    const float4* x4 = (const float4*)(sX + (rbase+rr)*64);
    float acc = 0.f;
#pragma unroll
    for (int kk=0; kk<16; kk++){ float4 c=x4[kk], w=wv[kk];
      acc += c.x*w.x + c.y*w.y + c.z*w.z + c.w*w.w; }
    int row = row0 + rbase + rr;
    h[(size_t)row*64 + f] = acc;
    float a = acc * as, d = acc * ad;
#pragma unroll
    for (int o = 32; o >= 1; o >>= 1){
      a += __shfl_xor(a, o);
      d += __shfl_xor(d, o);
    }
    if (f == 0){ asv[row] = a; adv[row] = d; }
  }
}

// ================= GAT fused online-softmax aggregate =================
// lane=(row,quarter); flash-style running (m,den,acc); self-loop included.
__global__ __launch_bounds__(256) void gat_agg(
    const float* __restrict__ h, const int* __restrict__ rowptr,
    const int* __restrict__ col, const float* __restrict__ asv,
    const float* __restrict__ adv, const float* __restrict__ bias,
    float* __restrict__ out, int do_relu){
  __shared__ int srp[65];
  int t = threadIdx.x;
  int row0 = blockIdx.x * 64;
  if (t < 65) srp[t] = rowptr[row0 + t];
  __syncthreads();
  int l = t & 63;
  int r = ((t >> 6) << 4) + (l >> 2);
  int q = l & 3;
  int v = row0 + r;
  int beg = srp[r], end = srp[r+1];
  float advv = adv[v];
  float m = lrelu(asv[v] + advv);   // self term, weight exp(0)=1
  float den = 1.f;
  const float4* hb = (const float4*)h;
  const float4* pv = hb + (size_t)v*16 + q*4;
  float4 a0 = pv[0], a1 = pv[1], a2 = pv[2], a3 = pv[3];
  int j = beg;
  for (; j + 2 <= end; j += 2){
    int s0 = col[j], s1 = col[j+1];
    float e0 = lrelu(asv[s0] + advv), e1 = lrelu(asv[s1] + advv);
    const float4* p0 = hb + (size_t)s0*16 + q*4;
    const float4* p1 = hb + (size_t)s1*16 + q*4;
    float cm = fmaxf(e0, e1);
    if (cm > m){
      float sc = expf(m - cm);
      den *= sc; mul4(a0,sc); mul4(a1,sc); mul4(a2,sc); mul4(a3,sc);
      m = cm;
    }
    float w0 = expf(e0 - m), w1 = expf(e1 - m);
    den += w0 + w1;
    fma4(a0,w0,p0[0]); fma4(a1,w0,p0[1]); fma4(a2,w0,p0[2]); fma4(a3,w0,p0[3]);
    fma4(a0,w1,p1[0]); fma4(a1,w1,p1[1]); fma4(a2,w1,p1[2]); fma4(a3,w1,p1[3]);
  }
  if (j < end){
    int s0 = col[j];
    float e0 = lrelu(asv[s0] + advv);
    const float4* p0 = hb + (size_t)s0*16 + q*4;
    if (e0 > m){
      float sc = expf(m - e0);
      den *= sc; mul4(a0,sc); mul4(a1,sc); mul4(a2,sc); mul4(a3,sc);
      m = e0;
    }
    float w0 = expf(e0 - m);
    den += w0;
    fma4(a0,w0,p0[0]); fma4(a1,w0,p0[1]); fma4(a2,w0,p0[2]); fma4(a3,w0,p0[3]);
  }
  float rden = 1.f / fmaxf(den, 1e-16f);
  const float4* b4 = (const float4*)bias;
  float4 bb0=b4[q*4], bb1=b4[q*4+1], bb2=b4[q*4+2], bb3=b4[q*4+3];
  mul4(a0,rden); mul4(a1,rden); mul4(a2,rden); mul4(a3,rden);
  add4(a0,bb0); add4(a1,bb1); add4(a2,bb2); add4(a3,bb3);
  if (do_relu){
    a0.x=fmaxf(a0.x,0.f); a0.y=fmaxf(a0.y,0.f); a0.z=fmaxf(a0.z,0.f); a0.w=fmaxf(a0.w,0.f);
    a1.x=fmaxf(a1.x,0.f); a1.y=fmaxf(a1.y,0.f); a1.z=fmaxf(a1.z,0.f); a1.w=fmaxf(a1.w,0.f);
    a2.x=fmaxf(a2.x,0.f); a2.y=fmaxf(a2.y,0.f); a2.z=fmaxf(a2.z,0.f); a2.w=fmaxf(a2.w,0.f);
    a3.x=fmaxf(a3.x,0.f); a3.y=fmaxf(a3.y,0.f); a3.z=fmaxf(a3.z,0.f); a3.w=fmaxf(a3.w,0.f);
  }
  float4* o4 = (float4*)out + (size_t)v*16 + q*4;
  o4[0]=a0; o4[1]=a1; o4[2]=a2; o4[3]=a3;
}

// ================= fused MLP 64->64->32->16 (64 rows/block) =================
__global__ __launch_bounds__(256) void mlp3(
    const float* __restrict__ in,
    const float* __restrict__ w1, const float* __restrict__ b1,
    const float* __restrict__ w2, const float* __restrict__ b2,
    const float* __restrict__ w3, const float* __restrict__ b3,
    float* __restrict__ out){
  __shared__ float sX[64*64];
  __shared__ float sH1[64*64];
  __shared__ float sH2[64*32];
  int t = threadIdx.x, f = t & 63;
  int row0 = blockIdx.x * 64;
  {
    float4* d = (float4*)sX;
    const float4* g = (const float4*)(in + (size_t)row0*64);
#pragma unroll
    for (int i=0;i<4;i++) d[t + i*256] = g[t + i*256];
  }
  int rbase = (t >> 6) * 16;
  float4 wv[16];
  { const float4* W4 = (const float4*)(w1 + f*64);
#pragma unroll
    for (int kk=0; kk<16; kk++) wv[kk] = W4[kk]; }
  float bf = b1[f];
  __syncthreads();
#pragma unroll
  for (int rr=0; rr<16; rr++){
    const float4* x4 = (const float4*)(sX + (rbase+rr)*64);
    float acc = bf;
#pragma unroll
    for (int kk=0; kk<16; kk++){ float4 c=x4[kk], w=wv[kk];
      acc += c.x*w.x + c.y*w.y + c.z*w.z + c.w*w.w; }
    sH1[(rbase+rr)*64 + f] = fmaxf(acc, 0.f);
  }
  __syncthreads();
  int f2 = f & 31, hi = f >> 5;
  { const float4* W4 = (const float4*)(w2 + f2*64);
#pragma unroll
    for (int kk=0; kk<16; kk++) wv[kk] = W4[kk]; }
  float bf2 = b2[f2];
#pragma unroll
  for (int rr=0; rr<8; rr++){
    int rloc = rbase + rr*2 + hi;
    const float4* x4 = (const float4*)(sH1 + rloc*64);
    float acc = bf2;
#pragma unroll
    for (int kk=0; kk<16; kk++){ float4 c=x4[kk], w=wv[kk];
      acc += c.x*w.x + c.y*w.y + c.z*w.z + c.w*w.w; }
    sH2[rloc*32 + f2] = fmaxf(acc, 0.f);
  }
  __syncthreads();
  int f3 = f & 15, hi2 = f >> 4;
  float4 w3v[8];
  { const float4* W4 = (const float4*)(w3 + f3*32);
#pragma unroll
    for (int kk=0; kk<8; kk++) w3v[kk] = W4[kk]; }
  float bf3 = b3[f3];
#pragma unroll
  for (int rr=0; rr<4; rr++){
    int rloc = rbase + rr*4 + hi2;
    const float4* x4 = (const float4*)(sH2 + rloc*32);
    float acc = bf3;
#pragma unroll
    for (int kk=0; kk<8; kk++){ float4 c=x4[kk], w=w3v[kk];
      acc += c.x*w.x + c.y*w.y + c.z*w.z + c.w*w.w; }
    out[(size_t)(row0+rloc)*16 + f3] = acc;
  }
}

extern "C" void kernel_launch(void* const* d_in, const int* in_sizes, int n_in,
                              void* d_out, int out_size, void* d_ws, size_t ws_size,
                              hipStream_t stream) {
    const float* x        = (const float*)d_in[0];
    const int*   ei       = (const int*)d_in[1];
    const float* sage_Wl  = (const float*)d_in[2];
    const float* sage_Wr  = (const float*)d_in[3];
    const float* sage_b   = (const float*)d_in[4];
    const float* gat_W    = (const float*)d_in[5];
    const float* gat_as   = (const float*)d_in[6];
    const float* gat_ad   = (const float*)d_in[7];
    const float* gat_b    = (const float*)d_in[8];
    const float* p1W = (const float*)d_in[9],  *p1b = (const float*)d_in[10];
    const float* p2W = (const float*)d_in[11], *p2b = (const float*)d_in[12];
    const float* p3W = (const float*)d_in[13], *p3b = (const float*)d_in[14];

    int n = in_sizes[0] / 64;        // 262144
    int E = in_sizes[1] / 2;         // 1048576
    const int* src = ei;
    const int* dst = ei + E;

    size_t N64 = (size_t)n * 64;
    float* bufA   = (float*)d_ws;
    float* bufB   = bufA + N64;
    int*   rowptr = (int*)(bufB + N64);
    int*   wp     = rowptr + (n + 1);
    int*   col    = wp + n;
    int*   bsum   = col + E;
    float* asv    = (float*)(bsum + 1024);
    float* adv    = asv + n;

    int nb = n / 256;                 // 1024

    // ---- CSR build ----
    hipMemsetAsync(wp, 0, (size_t)n * 4, stream);
    deg_count<<<(E + 255) / 256, 256, 0, stream>>>(dst, wp, E);
    scan_block<<<nb, 256, 0, stream>>>(wp, rowptr, bsum);
    scan_top<<<1, 256, 0, stream>>>(bsum);
    scan_add<<<nb, 256, 0, stream>>>(rowptr, bsum);
    copy_wp<<<nb, 256, 0, stream>>>(rowptr, wp);
    fill_csr<<<(E + 255) / 256, 256, 0, stream>>>(src, dst, wp, col, E);

    // ---- 4 SAGE layers ----
    const float* cur = x;
    float* nxt = bufA;
    for (int l = 0; l < 4; l++){
        sage_fused<<<n / 64, 256, 0, stream>>>(cur, rowptr, col,
            sage_Wl + l*4096, sage_Wr + l*4096, sage_b + l*64, nxt, l < 3 ? 1 : 0);
        cur = nxt;
        nxt = (nxt == bufA) ? bufB : bufA;
    }
    // cur = bufB, nxt = bufA

    // ---- 3 GAT layers ----
    for (int l = 0; l < 3; l++){
        gat_gemm_attn<<<n / 64, 256, 0, stream>>>(cur, gat_W + l*4096,
            gat_as + l*64, gat_ad + l*64, nxt, asv, adv);
        gat_agg<<<n / 64, 256, 0, stream>>>(nxt, rowptr, col, asv, adv,
            gat_b + l*64, (float*)cur, l < 2 ? 1 : 0);
    }

    // ---- projection MLP ----
    mlp3<<<n / 64, 256, 0, stream>>>(cur, p1W, p1b, p2W, p2b, p3W, p3b, (float*)d_out);
}

// Round 5
// 975.899 us; speedup vs baseline: 9.3787x; 1.1562x over previous
//
#include <hip/hip_runtime.h>
#include <type_traits>
#include <utility>

typedef __attribute__((ext_vector_type(4))) float f32x4;
typedef __attribute__((ext_vector_type(8))) short short8v;
typedef __attribute__((ext_vector_type(8))) unsigned short ushort8v;
typedef __attribute__((ext_vector_type(8))) __bf16 bf16x8;

// --- pick whichever fragment type this ROCm's builtin accepts ---
template<typename T, typename = void> struct can_mfma : std::false_type {};
template<typename T> struct can_mfma<T, std::void_t<decltype(
  __builtin_amdgcn_mfma_f32_16x16x32_bf16(std::declval<T>(), std::declval<T>(),
                                          std::declval<f32x4>(), 0, 0, 0))>>
  : std::true_type {};
using frag_t = std::conditional_t<can_mfma<short8v>::value, short8v, bf16x8>;

__device__ __forceinline__ f32x4 MFMA(frag_t a, frag_t b, f32x4 c){
  return __builtin_amdgcn_mfma_f32_16x16x32_bf16(a, b, c, 0, 0, 0);
}

__device__ __forceinline__ unsigned short bfrn(float x){
  unsigned u = __float_as_uint(x);
  return (unsigned short)((u + 0x7FFFu + ((u >> 16) & 1u)) >> 16);
}
__device__ __forceinline__ float bf2f(unsigned short h){
  return __uint_as_float(((unsigned)h) << 16);
}
__device__ __forceinline__ float lrelu(float v){ return v > 0.f ? v : 0.2f*v; }
__device__ __forceinline__ void add4(float4& a, const float4 v){
  a.x += v.x; a.y += v.y; a.z += v.z; a.w += v.w; }
__device__ __forceinline__ void fma4(float4& a, float w, const float4 v){
  a.x += w*v.x; a.y += w*v.y; a.z += w*v.z; a.w += w*v.w; }
__device__ __forceinline__ void mul4(float4& a, float w){
  a.x *= w; a.y *= w; a.z *= w; a.w *= w; }

// ================= CSR build =================
__global__ void deg_count(const int* __restrict__ dst, int* __restrict__ deg, int E){
  int e = blockIdx.x*blockDim.x + threadIdx.x;
  if (e < E) atomicAdd(&deg[dst[e]], 1);
}

__global__ void scan_block(const int* __restrict__ deg, int* __restrict__ rowptr,
                           int* __restrict__ bsum){
  __shared__ int s[256];
  int t = threadIdx.x; int i = blockIdx.x*256 + t;
  int v = deg[i];
  s[t] = v; __syncthreads();
  for (int off=1; off<256; off<<=1){
    int a = (t>=off)? s[t-off] : 0; __syncthreads();
    s[t] += a; __syncthreads();
  }
  rowptr[i+1] = s[t];
  if (t==255) bsum[blockIdx.x] = s[255];
}

__global__ void scan_top(int* __restrict__ bsum){
  __shared__ int s[256];
  int t = threadIdx.x;
  int v0=bsum[t*4], v1=bsum[t*4+1], v2=bsum[t*4+2], v3=bsum[t*4+3];
  s[t] = v0+v1+v2+v3; __syncthreads();
  for (int off=1; off<256; off<<=1){
    int a = (t>=off)? s[t-off] : 0; __syncthreads();
    s[t] += a; __syncthreads();
  }
  int excl = (t==0)? 0 : s[t-1];
  bsum[t*4]   = excl;
  bsum[t*4+1] = excl+v0;
  bsum[t*4+2] = excl+v0+v1;
  bsum[t*4+3] = excl+v0+v1+v2;
}

__global__ void scan_add(int* __restrict__ rowptr, const int* __restrict__ bsum){
  int i = blockIdx.x*256 + threadIdx.x;
  rowptr[i+1] += bsum[blockIdx.x];
  if (i == 0) rowptr[0] = 0;
}

__global__ void copy_wp(const int* __restrict__ rowptr, int* __restrict__ wp){
  int i = blockIdx.x*256 + threadIdx.x;
  wp[i] = rowptr[i];
}

__global__ void fill_csr(const int* __restrict__ src, const int* __restrict__ dst,
                         int* __restrict__ wp, int* __restrict__ col, int E){
  int e = blockIdx.x*blockDim.x + threadIdx.x;
  if (e < E){
    int d = dst[e];
    int pos = atomicAdd(&wp[d], 1);
    col[pos] = src[e];
  }
}

// ================= weight pre-split: fp32 -> bf16 hi/lo =================
// layout: mats 0-3 sage_Wl, 4-7 sage_Wr, 8-10 gat_W ; each [64 out][64 in]
__global__ void prep_weights(const float* __restrict__ Wl, const float* __restrict__ Wr,
                             const float* __restrict__ Wg,
                             unsigned short* __restrict__ hi, unsigned short* __restrict__ lo){
  int i = blockIdx.x*256 + threadIdx.x;
  if (i >= 45056) return;
  float v;
  if (i < 16384) v = Wl[i];
  else if (i < 32768) v = Wr[i-16384];
  else v = Wg[i-32768];
  unsigned short hb = bfrn(v);
  hi[i] = hb;
  lo[i] = bfrn(v - bf2f(hb));
}

// ================= SAGE: gather-mean + split-bf16 MFMA dual GEMM =================
__global__ __launch_bounds__(256,4) void sage_mfma(
    const float* __restrict__ cur, const int* __restrict__ rowptr,
    const int* __restrict__ col,
    const unsigned short* __restrict__ WlHi, const unsigned short* __restrict__ WlLo,
    const unsigned short* __restrict__ WrHi, const unsigned short* __restrict__ WrLo,
    const float* __restrict__ bias, float* __restrict__ out, int do_relu){
  __shared__ __align__(16) unsigned short sMhi[64*64];
  __shared__ __align__(16) unsigned short sMlo[64*64];
  __shared__ int srp[65];
  int t = threadIdx.x;
  int row0 = blockIdx.x * 64;
  if (t < 65) srp[t] = rowptr[row0 + t];
  int w = t >> 6, l = t & 63;
  int lr = l & 15, lg = l >> 4;
  // ---- A-x fragments: own row slice from global, split hi/lo ----
  frag_t ax_hi[2], ax_lo[2];
  {
    int grow = row0 + w*16 + lr;
#pragma unroll
    for (int kt = 0; kt < 2; kt++){
      float vals[8];
      const float* p = cur + (size_t)grow*64 + kt*32 + lg*8;
      *(float4*)&vals[0] = *(const float4*)p;
      *(float4*)&vals[4] = *(const float4*)(p + 4);
      union { unsigned short u[8]; ushort8v v; } Uh, Ul;
#pragma unroll
      for (int j = 0; j < 8; j++){
        unsigned short hb = bfrn(vals[j]);
        Uh.u[j] = hb;
        Ul.u[j] = bfrn(vals[j] - bf2f(hb));
      }
      ax_hi[kt] = __builtin_bit_cast(frag_t, Uh.v);
      ax_lo[kt] = __builtin_bit_cast(frag_t, Ul.v);
    }
  }
  __syncthreads();
  // ---- gather-mean: 4 lanes/row, each owns 16 features; write bf16 hi/lo LDS ----
  {
    int r = (w << 4) + (l >> 2);
    int q = l & 3;
    int beg = srp[r], end = srp[r+1];
    const float4* base4 = (const float4*)cur;
    float4 a0 = {0,0,0,0}, a1 = a0, a2 = a0, a3 = a0;
    int j = beg;
    for (; j + 2 <= end; j += 2){
      int s0 = col[j], s1 = col[j+1];
      const float4* p0 = base4 + (size_t)s0*16 + q*4;
      const float4* p1 = base4 + (size_t)s1*16 + q*4;
      float4 u0=p0[0], u1=p0[1], u2=p0[2], u3=p0[3];
      float4 w0=p1[0], w1=p1[1], w2=p1[2], w3=p1[3];
      add4(a0,u0); add4(a1,u1); add4(a2,u2); add4(a3,u3);
      add4(a0,w0); add4(a1,w1); add4(a2,w2); add4(a3,w3);
    }
    if (j < end){
      int s0 = col[j];
      const float4* p0 = base4 + (size_t)s0*16 + q*4;
      add4(a0,p0[0]); add4(a1,p0[1]); add4(a2,p0[2]); add4(a3,p0[3]);
    }
    float rdeg = 1.f / fmaxf((float)(end-beg), 1.f);
    mul4(a0,rdeg); mul4(a1,rdeg); mul4(a2,rdeg); mul4(a3,rdeg);
    float mv[16];
    *(float4*)&mv[0]  = a0; *(float4*)&mv[4]  = a1;
    *(float4*)&mv[8]  = a2; *(float4*)&mv[12] = a3;
#pragma unroll
    for (int hh = 0; hh < 2; hh++){
      union { unsigned short u[8]; ushort8v v; } Uh, Ul;
#pragma unroll
      for (int j2 = 0; j2 < 8; j2++){
        float xx = mv[hh*8 + j2];
        unsigned short hb = bfrn(xx);
        Uh.u[j2] = hb;
        Ul.u[j2] = bfrn(xx - bf2f(hb));
      }
      int slot = (2*q + hh) ^ (r & 7);
      *(ushort8v*)&sMhi[r*64 + slot*8] = Uh.v;
      *(ushort8v*)&sMlo[r*64 + slot*8] = Ul.v;
    }
  }
  __syncthreads();
  // ---- MFMA GEMM: wave w -> rows row0+w*16 .. +15 ----
  int rl = (w << 4) + lr;
  frag_t am_hi[2], am_lo[2];
#pragma unroll
  for (int kt = 0; kt < 2; kt++){
    int slot = (kt*4 + lg) ^ (rl & 7);
    am_hi[kt] = __builtin_bit_cast(frag_t, *(const ushort8v*)&sMhi[rl*64 + slot*8]);
    am_lo[kt] = __builtin_bit_cast(frag_t, *(const ushort8v*)&sMlo[rl*64 + slot*8]);
  }
#pragma unroll
  for (int ct = 0; ct < 4; ct++){
    float bv = bias[ct*16 + lr];
    f32x4 acc = {bv, bv, bv, bv};
#pragma unroll
    for (int kt = 0; kt < 2; kt++){
      int wo = (ct*16 + lr)*64 + kt*32 + lg*8;
      frag_t blh = __builtin_bit_cast(frag_t, *(const ushort8v*)&WlHi[wo]);
      frag_t bll = __builtin_bit_cast(frag_t, *(const ushort8v*)&WlLo[wo]);
      acc = MFMA(am_hi[kt], blh, acc);
      acc = MFMA(am_lo[kt], blh, acc);
      acc = MFMA(am_hi[kt], bll, acc);
      frag_t brh = __builtin_bit_cast(frag_t, *(const ushort8v*)&WrHi[wo]);
      frag_t brl = __builtin_bit_cast(frag_t, *(const ushort8v*)&WrLo[wo]);
      acc = MFMA(ax_hi[kt], brh, acc);
      acc = MFMA(ax_lo[kt], brh, acc);
      acc = MFMA(ax_hi[kt], brl, acc);
    }
#pragma unroll
    for (int r = 0; r < 4; r++){
      float v = acc[r];
      if (do_relu) v = fmaxf(v, 0.f);
      out[(size_t)(row0 + w*16 + lg*4 + r)*64 + ct*16 + lr] = v;
    }
  }
}

// ================= GAT: split-bf16 MFMA GEMM + fused attention dots =================
__global__ __launch_bounds__(256,4) void gat_mfma(
    const float* __restrict__ cur,
    const unsigned short* __restrict__ WHi, const unsigned short* __restrict__ WLo,
    const float* __restrict__ a_src, const float* __restrict__ a_dst,
    float* __restrict__ h, float* __restrict__ asv, float* __restrict__ adv){
  int t = threadIdx.x;
  int row0 = blockIdx.x * 64;
  int w = t >> 6, l = t & 63;
  int lr = l & 15, lg = l >> 4;
  frag_t ax_hi[2], ax_lo[2];
  {
    int grow = row0 + w*16 + lr;
#pragma unroll
    for (int kt = 0; kt < 2; kt++){
      float vals[8];
      const float* p = cur + (size_t)grow*64 + kt*32 + lg*8;
      *(float4*)&vals[0] = *(const float4*)p;
      *(float4*)&vals[4] = *(const float4*)(p + 4);
      union { unsigned short u[8]; ushort8v v; } Uh, Ul;
#pragma unroll
      for (int j = 0; j < 8; j++){
        unsigned short hb = bfrn(vals[j]);
        Uh.u[j] = hb;
        Ul.u[j] = bfrn(vals[j] - bf2f(hb));
      }
      ax_hi[kt] = __builtin_bit_cast(frag_t, Uh.v);
      ax_lo[kt] = __builtin_bit_cast(frag_t, Ul.v);
    }
  }
  float pav[4] = {0,0,0,0}, pdv[4] = {0,0,0,0};
#pragma unroll
  for (int ct = 0; ct < 4; ct++){
    f32x4 acc = {0,0,0,0};
#pragma unroll
    for (int kt = 0; kt < 2; kt++){
      int wo = (ct*16 + lr)*64 + kt*32 + lg*8;
      frag_t bh = __builtin_bit_cast(frag_t, *(const ushort8v*)&WHi[wo]);
      frag_t bl = __builtin_bit_cast(frag_t, *(const ushort8v*)&WLo[wo]);
      acc = MFMA(ax_hi[kt], bh, acc);
      acc = MFMA(ax_lo[kt], bh, acc);
      acc = MFMA(ax_hi[kt], bl, acc);
    }
    float asc = a_src[ct*16 + lr], adc = a_dst[ct*16 + lr];
#pragma unroll
    for (int r = 0; r < 4; r++){
      float v = acc[r];
      h[(size_t)(row0 + w*16 + lg*4 + r)*64 + ct*16 + lr] = v;
      pav[r] += v * asc;
      pdv[r] += v * adc;
    }
  }
#pragma unroll
  for (int off = 1; off < 16; off <<= 1){
#pragma unroll
    for (int r = 0; r < 4; r++){
      pav[r] += __shfl_xor(pav[r], off);
      pdv[r] += __shfl_xor(pdv[r], off);
    }
  }
  if (lr == 0){
#pragma unroll
    for (int r = 0; r < 4; r++){
      int row = row0 + w*16 + lg*4 + r;
      asv[row] = pav[r];
      adv[row] = pdv[r];
    }
  }
}

// ================= GAT fused online-softmax aggregate (unchanged) =================
__global__ __launch_bounds__(256) void gat_agg(
    const float* __restrict__ h, const int* __restrict__ rowptr,
    const int* __restrict__ col, const float* __restrict__ asv,
    const float* __restrict__ adv, const float* __restrict__ bias,
    float* __restrict__ out, int do_relu){
  __shared__ int srp[65];
  int t = threadIdx.x;
  int row0 = blockIdx.x * 64;
  if (t < 65) srp[t] = rowptr[row0 + t];
  __syncthreads();
  int l = t & 63;
  int r = ((t >> 6) << 4) + (l >> 2);
  int q = l & 3;
  int v = row0 + r;
  int beg = srp[r], end = srp[r+1];
  float advv = adv[v];
  float m = lrelu(asv[v] + advv);
  float den = 1.f;
  const float4* hb = (const float4*)h;
  const float4* pv = hb + (size_t)v*16 + q*4;
  float4 a0 = pv[0], a1 = pv[1], a2 = pv[2], a3 = pv[3];
  int j = beg;
  for (; j + 2 <= end; j += 2){
    int s0 = col[j], s1 = col[j+1];
    float e0 = lrelu(asv[s0] + advv), e1 = lrelu(asv[s1] + advv);
    const float4* p0 = hb + (size_t)s0*16 + q*4;
    const float4* p1 = hb + (size_t)s1*16 + q*4;
    float cm = fmaxf(e0, e1);
    if (cm > m){
      float sc = expf(m - cm);
      den *= sc; mul4(a0,sc); mul4(a1,sc); mul4(a2,sc); mul4(a3,sc);
      m = cm;
    }
    float w0 = expf(e0 - m), w1 = expf(e1 - m);
    den += w0 + w1;
    fma4(a0,w0,p0[0]); fma4(a1,w0,p0[1]); fma4(a2,w0,p0[2]); fma4(a3,w0,p0[3]);
    fma4(a0,w1,p1[0]); fma4(a1,w1,p1[1]); fma4(a2,w1,p1[2]); fma4(a3,w1,p1[3]);
  }
  if (j < end){
    int s0 = col[j];
    float e0 = lrelu(asv[s0] + advv);
    const float4* p0 = hb + (size_t)s0*16 + q*4;
    if (e0 > m){
      float sc = expf(m - e0);
      den *= sc; mul4(a0,sc); mul4(a1,sc); mul4(a2,sc); mul4(a3,sc);
      m = e0;
    }
    float w0 = expf(e0 - m);
    den += w0;
    fma4(a0,w0,p0[0]); fma4(a1,w0,p0[1]); fma4(a2,w0,p0[2]); fma4(a3,w0,p0[3]);
  }
  float rden = 1.f / fmaxf(den, 1e-16f);
  const float4* b4 = (const float4*)bias;
  float4 bb0=b4[q*4], bb1=b4[q*4+1], bb2=b4[q*4+2], bb3=b4[q*4+3];
  mul4(a0,rden); mul4(a1,rden); mul4(a2,rden); mul4(a3,rden);
  add4(a0,bb0); add4(a1,bb1); add4(a2,bb2); add4(a3,bb3);
  if (do_relu){
    a0.x=fmaxf(a0.x,0.f); a0.y=fmaxf(a0.y,0.f); a0.z=fmaxf(a0.z,0.f); a0.w=fmaxf(a0.w,0.f);
    a1.x=fmaxf(a1.x,0.f); a1.y=fmaxf(a1.y,0.f); a1.z=fmaxf(a1.z,0.f); a1.w=fmaxf(a1.w,0.f);
    a2.x=fmaxf(a2.x,0.f); a2.y=fmaxf(a2.y,0.f); a2.z=fmaxf(a2.z,0.f); a2.w=fmaxf(a2.w,0.f);
    a3.x=fmaxf(a3.x,0.f); a3.y=fmaxf(a3.y,0.f); a3.z=fmaxf(a3.z,0.f); a3.w=fmaxf(a3.w,0.f);
  }
  float4* o4 = (float4*)out + (size_t)v*16 + q*4;
  o4[0]=a0; o4[1]=a1; o4[2]=a2; o4[3]=a3;
}

// ================= fused MLP 64->64->32->16 (unchanged) =================
__global__ __launch_bounds__(256) void mlp3(
    const float* __restrict__ in,
    const float* __restrict__ w1, const float* __restrict__ b1,
    const float* __restrict__ w2, const float* __restrict__ b2,
    const float* __restrict__ w3, const float* __restrict__ b3,
    float* __restrict__ out){
  __shared__ float sX[64*64];
  __shared__ float sH1[64*64];
  __shared__ float sH2[64*32];
  int t = threadIdx.x, f = t & 63;
  int row0 = blockIdx.x * 64;
  {
    float4* d = (float4*)sX;
    const float4* g = (const float4*)(in + (size_t)row0*64);
#pragma unroll
    for (int i=0;i<4;i++) d[t + i*256] = g[t + i*256];
  }
  int rbase = (t >> 6) * 16;
  float4 wv[16];
  { const float4* W4 = (const float4*)(w1 + f*64);
#pragma unroll
    for (int kk=0; kk<16; kk++) wv[kk] = W4[kk]; }
  float bf = b1[f];
  __syncthreads();
#pragma unroll
  for (int rr=0; rr<16; rr++){
    const float4* x4 = (const float4*)(sX + (rbase+rr)*64);
    float acc = bf;
#pragma unroll
    for (int kk=0; kk<16; kk++){ float4 c=x4[kk], w=wv[kk];
      acc += c.x*w.x + c.y*w.y + c.z*w.z + c.w*w.w; }
    sH1[(rbase+rr)*64 + f] = fmaxf(acc, 0.f);
  }
  __syncthreads();
  int f2 = f & 31, hi = f >> 5;
  { const float4* W4 = (const float4*)(w2 + f2*64);
#pragma unroll
    for (int kk=0; kk<16; kk++) wv[kk] = W4[kk]; }
  float bf2 = b2[f2];
#pragma unroll
  for (int rr=0; rr<8; rr++){
    int rloc = rbase + rr*2 + hi;
    const float4* x4 = (const float4*)(sH1 + rloc*64);
    float acc = bf2;
#pragma unroll
    for (int kk=0; kk<16; kk++){ float4 c=x4[kk], w=wv[kk];
      acc += c.x*w.x + c.y*w.y + c.z*w.z + c.w*w.w; }
    sH2[rloc*32 + f2] = fmaxf(acc, 0.f);
  }
  __syncthreads();
  int f3 = f & 15, hi2 = f >> 4;
  float4 w3v[8];
  { const float4* W4 = (const float4*)(w3 + f3*32);
#pragma unroll
    for (int kk=0; kk<8; kk++) w3v[kk] = W4[kk]; }
  float bf3 = b3[f3];
#pragma unroll
  for (int rr=0; rr<4; rr++){
    int rloc = rbase + rr*4 + hi2;
    const float4* x4 = (const float4*)(sH2 + rloc*32);
    float acc = bf3;
#pragma unroll
    for (int kk=0; kk<8; kk++){ float4 c=x4[kk], w=w3v[kk];
      acc += c.x*w.x + c.y*w.y + c.z*w.z + c.w*w.w; }
    out[(size_t)(row0+rloc)*16 + f3] = acc;
  }
}

extern "C" void kernel_launch(void* const* d_in, const int* in_sizes, int n_in,
                              void* d_out, int out_size, void* d_ws, size_t ws_size,
                              hipStream_t stream) {
    const float* x        = (const float*)d_in[0];
    const int*   ei       = (const int*)d_in[1];
    const float* sage_Wl  = (const float*)d_in[2];
    const float* sage_Wr  = (const float*)d_in[3];
    const float* sage_b   = (const float*)d_in[4];
    const float* gat_W    = (const float*)d_in[5];
    const float* gat_as   = (const float*)d_in[6];
    const float* gat_ad   = (const float*)d_in[7];
    const float* gat_b    = (const float*)d_in[8];
    const float* p1W = (const float*)d_in[9],  *p1b = (const float*)d_in[10];
    const float* p2W = (const float*)d_in[11], *p2b = (const float*)d_in[12];
    const float* p3W = (const float*)d_in[13], *p3b = (const float*)d_in[14];

    int n = in_sizes[0] / 64;        // 262144
    int E = in_sizes[1] / 2;         // 1048576
    const int* src = ei;
    const int* dst = ei + E;

    size_t N64 = (size_t)n * 64;
    float* bufA   = (float*)d_ws;
    float* bufB   = bufA + N64;
    int*   rowptr = (int*)(bufB + N64);          // n+4 ints (padded for alignment)
    int*   wp     = rowptr + (n + 4);            // 16B-aligned; reused for weights after CSR
    int*   col    = wp + n;
    int*   bsum   = col + E;
    float* asv    = (float*)(bsum + 1024);
    float* adv    = asv + n;

    unsigned short* whi = (unsigned short*)wp;   // 45056 ushorts (90KB) - wp is dead post-CSR
    unsigned short* wlo = whi + 45056;

    int nb = n / 256;                 // 1024

    // ---- CSR build ----
    hipMemsetAsync(wp, 0, (size_t)n * 4, stream);
    deg_count<<<(E + 255) / 256, 256, 0, stream>>>(dst, wp, E);
    scan_block<<<nb, 256, 0, stream>>>(wp, rowptr, bsum);
    scan_top<<<1, 256, 0, stream>>>(bsum);
    scan_add<<<nb, 256, 0, stream>>>(rowptr, bsum);
    copy_wp<<<nb, 256, 0, stream>>>(rowptr, wp);
    fill_csr<<<(E + 255) / 256, 256, 0, stream>>>(src, dst, wp, col, E);

    // ---- weight pre-split (wp is free now) ----
    prep_weights<<<176, 256, 0, stream>>>(sage_Wl, sage_Wr, gat_W, whi, wlo);

    // ---- 4 SAGE layers ----
    const float* cur = x;
    float* nxt = bufA;
    for (int l = 0; l < 4; l++){
        sage_mfma<<<n / 64, 256, 0, stream>>>(cur, rowptr, col,
            whi + l*4096,          wlo + l*4096,
            whi + 16384 + l*4096,  wlo + 16384 + l*4096,
            sage_b + l*64, nxt, l < 3 ? 1 : 0);
        cur = nxt;
        nxt = (nxt == bufA) ? bufB : bufA;
    }
    // cur = bufB, h buffer = bufA

    // ---- 3 GAT layers ----
    for (int l = 0; l < 3; l++){
        gat_mfma<<<n / 64, 256, 0, stream>>>(cur,
            whi + 32768 + l*4096, wlo + 32768 + l*4096,
            gat_as + l*64, gat_ad + l*64, nxt, asv, adv);
        gat_agg<<<n / 64, 256, 0, stream>>>(nxt, rowptr, col, asv, adv,
            gat_b + l*64, (float*)cur, l < 2 ? 1 : 0);
    }

    // ---- projection MLP ----
    mlp3<<<n / 64, 256, 0, stream>>>(cur, p1W, p1b, p2W, p2b, p3W, p3b, (float*)d_out);
}